// Round 2
// baseline (683.124 us; speedup 1.0000x reference)
//
#include <hip/hip_runtime.h>
#include <math.h>

// DotProductAttention: B=64, S=2048, D=1024, fp32.
// Fused one-pass online-softmax attention (flash-style, 1 query/batch).
// Kernel 1: per (b, chunk) block computes partial (m, l, acc[D]) over its S-chunk.
// Kernel 2: per-b combine of chunk partials + divide by l, write [B, 1, D].

#define BB 64
#define SS 2048
#define DD 1024
#define CHUNKS 32
#define S_CHUNK (SS / CHUNKS)      // 64 rows per block
#define PARTIAL_STRIDE 1032        // floats: [m, l, 6 pad, acc[1024]] -> 4128 B (16B-aligned)

__global__ __launch_bounds__(256) void attn_partial(
    const float* __restrict__ h,       // [B, D] (leading 1 dim dropped)
    const float* __restrict__ enc,     // [B, S, D]
    float* __restrict__ ws)            // [B*CHUNKS, PARTIAL_STRIDE]
{
    const int bc   = blockIdx.x;
    const int b    = bc / CHUNKS;
    const int c    = bc % CHUNKS;
    const int tid  = threadIdx.x;
    const int lane = tid & 63;
    const int wave = tid >> 6;

    // ---- load this lane's h_t fragment: element d = j*256 + lane*4 + k
    float hf[16];
    const float4* hp = reinterpret_cast<const float4*>(h + (size_t)b * DD);
    #pragma unroll
    for (int j = 0; j < 4; ++j) {
        float4 v = hp[j * 64 + lane];
        hf[j*4+0] = v.x; hf[j*4+1] = v.y; hf[j*4+2] = v.z; hf[j*4+3] = v.w;
    }

    // ---- online softmax state (per wave; acc distributed across lanes)
    float m = -INFINITY;
    float l = 0.f;
    float acc[16];
    #pragma unroll
    for (int i = 0; i < 16; ++i) acc[i] = 0.f;

    const float4* ep = reinterpret_cast<const float4*>(enc);
    const int s_end = (c + 1) * S_CHUNK;

    // 2 rows per iteration: rows s and s+4 (waves interleave with stride 4)
    for (int s = c * S_CHUNK + wave; s < s_end; s += 8) {
        const size_t base0 = ((size_t)(b * SS + s) * DD) >> 2;   // float4 idx of row s
        const size_t base1 = base0 + (4 * DD / 4);               // row s+4

        float4 r0[4], r1[4];
        #pragma unroll
        for (int j = 0; j < 4; ++j) r0[j] = ep[base0 + j * 64 + lane];
        #pragma unroll
        for (int j = 0; j < 4; ++j) r1[j] = ep[base1 + j * 64 + lane];

        // per-lane partial dots
        float dot0 = 0.f, dot1 = 0.f;
        #pragma unroll
        for (int j = 0; j < 4; ++j) {
            dot0 = fmaf(r0[j].x, hf[j*4+0], dot0);
            dot0 = fmaf(r0[j].y, hf[j*4+1], dot0);
            dot0 = fmaf(r0[j].z, hf[j*4+2], dot0);
            dot0 = fmaf(r0[j].w, hf[j*4+3], dot0);
        }
        #pragma unroll
        for (int j = 0; j < 4; ++j) {
            dot1 = fmaf(r1[j].x, hf[j*4+0], dot1);
            dot1 = fmaf(r1[j].y, hf[j*4+1], dot1);
            dot1 = fmaf(r1[j].z, hf[j*4+2], dot1);
            dot1 = fmaf(r1[j].w, hf[j*4+3], dot1);
        }
        // interleaved 64-lane butterfly reduces (independent chains)
        #pragma unroll
        for (int off = 32; off >= 1; off >>= 1) {
            dot0 += __shfl_xor(dot0, off, 64);
            dot1 += __shfl_xor(dot1, off, 64);
        }

        // online-softmax update, rescale deferred to max-increase (wave-uniform)
        const float m_new = fmaxf(m, fmaxf(dot0, dot1));
        if (m_new > m) {
            const float sc = __expf(m - m_new);   // exp(-inf)=0 handles first iter
            l *= sc;
            #pragma unroll
            for (int i = 0; i < 16; ++i) acc[i] *= sc;
            m = m_new;
        }
        const float p0 = __expf(dot0 - m);
        const float p1 = __expf(dot1 - m);
        l += p0 + p1;
        #pragma unroll
        for (int j = 0; j < 4; ++j) {
            acc[j*4+0] = fmaf(p1, r1[j].x, fmaf(p0, r0[j].x, acc[j*4+0]));
            acc[j*4+1] = fmaf(p1, r1[j].y, fmaf(p0, r0[j].y, acc[j*4+1]));
            acc[j*4+2] = fmaf(p1, r1[j].z, fmaf(p0, r0[j].z, acc[j*4+2]));
            acc[j*4+3] = fmaf(p1, r1[j].w, fmaf(p0, r0[j].w, acc[j*4+3]));
        }
    }

    // ---- combine the 4 waves of this block via LDS
    __shared__ float lds_acc[4][DD];   // 16 KiB
    __shared__ float lds_m[4], lds_l[4];

    #pragma unroll
    for (int j = 0; j < 4; ++j) {
        *reinterpret_cast<float4*>(&lds_acc[wave][j * 256 + lane * 4]) =
            make_float4(acc[j*4+0], acc[j*4+1], acc[j*4+2], acc[j*4+3]);
    }
    if (lane == 0) { lds_m[wave] = m; lds_l[wave] = l; }
    __syncthreads();

    const float m_b = fmaxf(fmaxf(lds_m[0], lds_m[1]), fmaxf(lds_m[2], lds_m[3]));
    const float e0 = __expf(lds_m[0] - m_b);
    const float e1 = __expf(lds_m[1] - m_b);
    const float e2 = __expf(lds_m[2] - m_b);
    const float e3 = __expf(lds_m[3] - m_b);

    float* outp = ws + (size_t)bc * PARTIAL_STRIDE;
    if (tid == 0) {
        outp[0] = m_b;
        outp[1] = e0 * lds_l[0] + e1 * lds_l[1] + e2 * lds_l[2] + e3 * lds_l[3];
    }

    // each of the 256 threads combines 4 d-positions
    const int d = tid * 4;
    float4 a0 = *reinterpret_cast<const float4*>(&lds_acc[0][d]);
    float4 a1 = *reinterpret_cast<const float4*>(&lds_acc[1][d]);
    float4 a2 = *reinterpret_cast<const float4*>(&lds_acc[2][d]);
    float4 a3 = *reinterpret_cast<const float4*>(&lds_acc[3][d]);
    float4 res;
    res.x = e0*a0.x + e1*a1.x + e2*a2.x + e3*a3.x;
    res.y = e0*a0.y + e1*a1.y + e2*a2.y + e3*a3.y;
    res.z = e0*a0.z + e1*a1.z + e2*a2.z + e3*a3.z;
    res.w = e0*a0.w + e1*a1.w + e2*a2.w + e3*a3.w;
    *reinterpret_cast<float4*>(outp + 8 + d) = res;
}

__global__ __launch_bounds__(256) void attn_combine(
    const float* __restrict__ ws,   // [B*CHUNKS, PARTIAL_STRIDE]
    float* __restrict__ out)        // [B, 1, D]
{
    const int b   = blockIdx.x;
    const int tid = threadIdx.x;
    const float* base = ws + (size_t)b * CHUNKS * PARTIAL_STRIDE;

    float m_g = -INFINITY;
    #pragma unroll
    for (int c = 0; c < CHUNKS; ++c)
        m_g = fmaxf(m_g, base[c * PARTIAL_STRIDE]);

    float e[CHUNKS];
    float L = 0.f;
    #pragma unroll
    for (int c = 0; c < CHUNKS; ++c) {
        e[c] = __expf(base[c * PARTIAL_STRIDE] - m_g);
        L += e[c] * base[c * PARTIAL_STRIDE + 1];
    }
    const float inv = 1.0f / L;

    const int d = tid * 4;
    float4 accv = make_float4(0.f, 0.f, 0.f, 0.f);
    #pragma unroll
    for (int c = 0; c < CHUNKS; ++c) {
        float4 v = *reinterpret_cast<const float4*>(base + c * PARTIAL_STRIDE + 8 + d);
        accv.x += e[c] * v.x;
        accv.y += e[c] * v.y;
        accv.z += e[c] * v.z;
        accv.w += e[c] * v.w;
    }
    accv.x *= inv; accv.y *= inv; accv.z *= inv; accv.w *= inv;
    *reinterpret_cast<float4*>(out + (size_t)b * DD + d) = accv;
}

extern "C" void kernel_launch(void* const* d_in, const int* in_sizes, int n_in,
                              void* d_out, int out_size, void* d_ws, size_t ws_size,
                              hipStream_t stream) {
    const float* h   = (const float*)d_in[0];   // [1, 64, 1024]
    const float* enc = (const float*)d_in[1];   // [64, 2048, 1024]
    float* out = (float*)d_out;                 // [64, 1, 1024]
    float* ws  = (float*)d_ws;                  // >= B*CHUNKS*PARTIAL_STRIDE*4 B ~ 8.5 MiB

    attn_partial<<<BB * CHUNKS, 256, 0, stream>>>(h, enc, ws);
    attn_combine<<<BB, 256, 0, stream>>>(ws, out);
}

// Round 4
// 656.312 us; speedup vs baseline: 1.0409x; 1.0409x over previous
//
#include <hip/hip_runtime.h>
#include <math.h>

// DotProductAttention: B=64, S=2048, D=1024, fp32.
// Fused one-pass online-softmax attention (flash-style, 1 query/batch).
// Kernel 1: per (b, chunk) block computes partial (m, l, acc[D]) over its S-chunk.
//           encoder_states is streamed with non-temporal loads (read exactly once).
// Kernel 2: 4 blocks per b (1 wave each) combine chunk partials + divide, write [B, 1, D].

#define BB 64
#define SS 2048
#define DD 1024
#define CHUNKS 32
#define S_CHUNK (SS / CHUNKS)      // 64 rows per block
#define PARTIAL_STRIDE 1032        // floats: [m, l, 6 pad, acc[1024]] -> 4128 B (16B-aligned)

typedef float f32x4 __attribute__((ext_vector_type(4)));

__global__ __launch_bounds__(256) void attn_partial(
    const float* __restrict__ h,       // [B, D] (leading 1 dim dropped)
    const float* __restrict__ enc,     // [B, S, D]
    float* __restrict__ ws)            // [B*CHUNKS, PARTIAL_STRIDE]
{
    const int bc   = blockIdx.x;
    const int b    = bc / CHUNKS;
    const int c    = bc % CHUNKS;
    const int tid  = threadIdx.x;
    const int lane = tid & 63;
    const int wave = tid >> 6;

    // ---- load this lane's h_t fragment: element d = j*256 + lane*4 + k
    float hf[16];
    const f32x4* hp = reinterpret_cast<const f32x4*>(h + (size_t)b * DD);
    #pragma unroll
    for (int j = 0; j < 4; ++j) {
        f32x4 v = hp[j * 64 + lane];
        hf[j*4+0] = v[0]; hf[j*4+1] = v[1]; hf[j*4+2] = v[2]; hf[j*4+3] = v[3];
    }

    // ---- online softmax state (per wave; acc distributed across lanes)
    float m = -INFINITY;
    float l = 0.f;
    float acc[16];
    #pragma unroll
    for (int i = 0; i < 16; ++i) acc[i] = 0.f;

    const f32x4* ep = reinterpret_cast<const f32x4*>(enc);
    const int s_end = (c + 1) * S_CHUNK;

    // 2 rows per iteration: rows s and s+4 (waves interleave with stride 4)
    for (int s = c * S_CHUNK + wave; s < s_end; s += 8) {
        const size_t base0 = ((size_t)(b * SS + s) * DD) >> 2;   // f32x4 idx of row s
        const size_t base1 = base0 + DD;                          // row s+4

        f32x4 r0[4], r1[4];
        #pragma unroll
        for (int j = 0; j < 4; ++j)
            r0[j] = __builtin_nontemporal_load(ep + base0 + j * 64 + lane);
        #pragma unroll
        for (int j = 0; j < 4; ++j)
            r1[j] = __builtin_nontemporal_load(ep + base1 + j * 64 + lane);

        // per-lane partial dots
        float dot0 = 0.f, dot1 = 0.f;
        #pragma unroll
        for (int j = 0; j < 4; ++j) {
            dot0 = fmaf(r0[j][0], hf[j*4+0], dot0);
            dot0 = fmaf(r0[j][1], hf[j*4+1], dot0);
            dot0 = fmaf(r0[j][2], hf[j*4+2], dot0);
            dot0 = fmaf(r0[j][3], hf[j*4+3], dot0);
        }
        #pragma unroll
        for (int j = 0; j < 4; ++j) {
            dot1 = fmaf(r1[j][0], hf[j*4+0], dot1);
            dot1 = fmaf(r1[j][1], hf[j*4+1], dot1);
            dot1 = fmaf(r1[j][2], hf[j*4+2], dot1);
            dot1 = fmaf(r1[j][3], hf[j*4+3], dot1);
        }
        // interleaved 64-lane butterfly reduces (independent chains)
        #pragma unroll
        for (int off = 32; off >= 1; off >>= 1) {
            dot0 += __shfl_xor(dot0, off, 64);
            dot1 += __shfl_xor(dot1, off, 64);
        }

        // online-softmax update, rescale deferred to max-increase (wave-uniform)
        const float m_new = fmaxf(m, fmaxf(dot0, dot1));
        if (m_new > m) {
            const float sc = __expf(m - m_new);   // exp(-inf)=0 handles first iter
            l *= sc;
            #pragma unroll
            for (int i = 0; i < 16; ++i) acc[i] *= sc;
            m = m_new;
        }
        const float p0 = __expf(dot0 - m);
        const float p1 = __expf(dot1 - m);
        l += p0 + p1;
        #pragma unroll
        for (int j = 0; j < 4; ++j) {
            acc[j*4+0] = fmaf(p1, r1[j][0], fmaf(p0, r0[j][0], acc[j*4+0]));
            acc[j*4+1] = fmaf(p1, r1[j][1], fmaf(p0, r0[j][1], acc[j*4+1]));
            acc[j*4+2] = fmaf(p1, r1[j][2], fmaf(p0, r0[j][2], acc[j*4+2]));
            acc[j*4+3] = fmaf(p1, r1[j][3], fmaf(p0, r0[j][3], acc[j*4+3]));
        }
    }

    // ---- combine the 4 waves of this block via LDS
    __shared__ float lds_acc[4][DD];   // 16 KiB
    __shared__ float lds_m[4], lds_l[4];

    #pragma unroll
    for (int j = 0; j < 4; ++j) {
        f32x4 v; v[0] = acc[j*4+0]; v[1] = acc[j*4+1]; v[2] = acc[j*4+2]; v[3] = acc[j*4+3];
        *reinterpret_cast<f32x4*>(&lds_acc[wave][j * 256 + lane * 4]) = v;
    }
    if (lane == 0) { lds_m[wave] = m; lds_l[wave] = l; }
    __syncthreads();

    const float m_b = fmaxf(fmaxf(lds_m[0], lds_m[1]), fmaxf(lds_m[2], lds_m[3]));
    const float e0 = __expf(lds_m[0] - m_b);
    const float e1 = __expf(lds_m[1] - m_b);
    const float e2 = __expf(lds_m[2] - m_b);
    const float e3 = __expf(lds_m[3] - m_b);

    float* outp = ws + (size_t)bc * PARTIAL_STRIDE;
    if (tid == 0) {
        outp[0] = m_b;
        outp[1] = e0 * lds_l[0] + e1 * lds_l[1] + e2 * lds_l[2] + e3 * lds_l[3];
    }

    // each of the 256 threads combines 4 d-positions
    const int d = tid * 4;
    f32x4 a0 = *reinterpret_cast<const f32x4*>(&lds_acc[0][d]);
    f32x4 a1 = *reinterpret_cast<const f32x4*>(&lds_acc[1][d]);
    f32x4 a2 = *reinterpret_cast<const f32x4*>(&lds_acc[2][d]);
    f32x4 a3 = *reinterpret_cast<const f32x4*>(&lds_acc[3][d]);
    f32x4 res = e0*a0 + e1*a1 + e2*a2 + e3*a3;
    *reinterpret_cast<f32x4*>(outp + 8 + d) = res;
}

// 4 blocks per b, 64 threads (1 wave) each; block covers 256 consecutive d's.
__global__ __launch_bounds__(64) void attn_combine(
    const float* __restrict__ ws,   // [B*CHUNKS, PARTIAL_STRIDE]
    float* __restrict__ out)        // [B, 1, D]
{
    const int b   = blockIdx.x >> 2;
    const int q   = blockIdx.x & 3;
    const int tid = threadIdx.x;
    const float* base = ws + (size_t)b * CHUNKS * PARTIAL_STRIDE;

    float m_g = -INFINITY;
    #pragma unroll
    for (int c = 0; c < CHUNKS; ++c)
        m_g = fmaxf(m_g, base[c * PARTIAL_STRIDE]);

    float e[CHUNKS];
    float L = 0.f;
    #pragma unroll
    for (int c = 0; c < CHUNKS; ++c) {
        e[c] = __expf(base[c * PARTIAL_STRIDE] - m_g);
        L += e[c] * base[c * PARTIAL_STRIDE + 1];
    }
    const float inv = 1.0f / L;

    const int d = q * 256 + tid * 4;     // this thread's float4 within D
    f32x4 accv = {0.f, 0.f, 0.f, 0.f};
    #pragma unroll
    for (int c = 0; c < CHUNKS; ++c) {
        f32x4 v = *reinterpret_cast<const f32x4*>(base + c * PARTIAL_STRIDE + 8 + d);
        accv += e[c] * v;
    }
    accv *= inv;
    *reinterpret_cast<f32x4*>(out + (size_t)b * DD + d) = accv;
}

extern "C" void kernel_launch(void* const* d_in, const int* in_sizes, int n_in,
                              void* d_out, int out_size, void* d_ws, size_t ws_size,
                              hipStream_t stream) {
    const float* h   = (const float*)d_in[0];   // [1, 64, 1024]
    const float* enc = (const float*)d_in[1];   // [64, 2048, 1024]
    float* out = (float*)d_out;                 // [64, 1, 1024]
    float* ws  = (float*)d_ws;                  // >= B*CHUNKS*PARTIAL_STRIDE*4 B ~ 8.5 MiB

    attn_partial<<<BB * CHUNKS, 256, 0, stream>>>(h, enc, ws);
    attn_combine<<<BB * 4, 64, 0, stream>>>(ws, out);
}